// Round 14
// baseline (328.887 us; speedup 1.0000x reference)
//
#include <hip/hip_runtime.h>
#include <math.h>

#define N_NODES 50000
#define N_EDGES 800000

typedef __attribute__((ext_vector_type(8))) short bf16x8;
typedef __attribute__((ext_vector_type(4))) float f32x4;

__device__ __forceinline__ short f2bf(float f){
  unsigned u = __float_as_uint(f);
  unsigned r = (u + 0x7FFFu + ((u >> 16) & 1u)) >> 16;
  return (short)r;
}
__device__ __forceinline__ unsigned pkbf(float lo, float hi){
  return (unsigned)(unsigned short)f2bf(lo) | ((unsigned)(unsigned short)f2bf(hi) << 16);
}

__device__ __forceinline__ float gelu_f(float x){
  float z = 0.7978845608028654f*(x + 0.044715f*x*x*x);
  float e = __expf(2.0f*z);
  return 0.5f*x*(2.0f - 2.0f/(e + 1.0f));   // 0.5x(1+tanh z), inf-safe
}

#define BF_LO(u) __uint_as_float((u)<<16)
#define BF_HI(u) __uint_as_float((u)&0xffff0000u)

// ---------------- unified weight prep: 5 transposes + Wqm fold + W1t + W2t ----------------
struct Prep {
  const float* src[5]; short* dst[5];
  const float* Wq; const float* We; const float* bq;
  short* Wtqm; float* bqm;
  const float* W1; short* W1t;
  const float* W2; short* W2t;
};
__global__ __launch_bounds__(256) void k_prep(Prep a){
  int blk = blockIdx.x, tid = threadIdx.x;
  if (blk < 320){
    int b = blk >> 6;
    int i = (blk & 63)*256 + tid;
    int n = i >> 7, k = i & 127;
    a.dst[b][n*128 + k] = f2bf(a.src[b][k*128 + n]);
  } else if (blk < 384){
    int i = (blk - 320)*256 + tid;
    int k = i >> 7, j = i & 127;
    int h = j >> 4, c = j & 15;
    float s = 0.f;
    #pragma unroll
    for (int dd = 0; dd < 16; ++dd)
      s += a.Wq[k*128 + h*16 + dd] * a.We[c*128 + h*16 + dd];
    a.Wtqm[j*128 + k] = f2bf(s);
    if (k == 0){
      float t = 0.f;
      #pragma unroll
      for (int dd = 0; dd < 16; ++dd)
        t += a.bq[h*16 + dd] * a.We[c*128 + h*16 + dd];
      a.bqm[j] = t;
    }
  } else if (blk < 640){
    int i = (blk - 384)*256 + tid;   // W1t [512][128] <- W1 [128][512]
    int n = i >> 7, k = i & 127;
    a.W1t[n*128 + k] = f2bf(a.W1[k*512 + n]);
  } else {
    int i = (blk - 640)*256 + tid;   // W2t [128][512] <- W2 [512][128]
    int n = i >> 9, k = i & 511;
    a.W2t[n*512 + k] = f2bf(a.W2[k*128 + n]);
  }
}

// ---------------- CSR build; also does the edge_attr passthrough copy ----------------
__global__ __launch_bounds__(256) void k_deg(const int* __restrict__ dst,
                                             const float* __restrict__ edge_attr,
                                             int* __restrict__ deg, float* __restrict__ eout){
  int i = blockIdx.x*256 + threadIdx.x;
  if (i < N_EDGES){
    atomicAdd(&deg[dst[i]], 1);
    const float* ea = edge_attr + (size_t)i*16;
    float4 a = *(const float4*)(ea+0), b = *(const float4*)(ea+4),
           c = *(const float4*)(ea+8), e = *(const float4*)(ea+12);
    float* op = eout + (size_t)i*16;
    *(float4*)(op+0)  = a;
    *(float4*)(op+4)  = b;
    *(float4*)(op+8)  = c;
    *(float4*)(op+12) = e;
  }
}

__global__ __launch_bounds__(256) void k_bsum(const int* __restrict__ deg,
                                              int* __restrict__ bsum, int* __restrict__ hist){
  __shared__ int lhist[64];
  __shared__ int wred[4];
  int tid = threadIdx.x;
  int i = blockIdx.x*256 + tid;
  if (tid < 64) lhist[tid] = 0;
  __syncthreads();
  int v = (i < N_NODES) ? deg[i] : 0;
  if (i < N_NODES) atomicAdd(&lhist[v > 63 ? 63 : v], 1);
  int s = v;
  #pragma unroll
  for (int sh = 32; sh >= 1; sh >>= 1) s += __shfl_xor(s, sh, 64);
  if ((tid & 63) == 0) wred[tid >> 6] = s;
  __syncthreads();
  if (tid == 0) bsum[blockIdx.x] = wred[0] + wred[1] + wred[2] + wred[3];
  if (tid < 64){ int c = lhist[tid]; if (c) atomicAdd(&hist[tid], c); }
}

__global__ __launch_bounds__(256) void k_bscan(const int* __restrict__ bsum, int* __restrict__ bbase,
                                               const int* __restrict__ hist, int* __restrict__ histcur){
  __shared__ int wsum[4];
  int tid = threadIdx.x;
  int v = (tid < 196) ? bsum[tid] : 0;
  int incl = v;
  #pragma unroll
  for (int s = 1; s < 64; s <<= 1){
    int t = __shfl_up(incl, s, 64);
    if ((tid & 63) >= s) incl += t;
  }
  if ((tid & 63) == 63) wsum[tid >> 6] = incl;
  __syncthreads();
  if (tid == 0){ int c = 0; for (int j = 0; j < 4; ++j){ int t = wsum[j]; wsum[j] = c; c += t; } }
  __syncthreads();
  if (tid < 196) bbase[tid] = wsum[tid >> 6] + (incl - v);
  if (tid < 64){
    int h = hist[tid];
    int inc = h;
    #pragma unroll
    for (int s = 1; s < 64; s <<= 1){
      int t = __shfl_up(inc, s, 64);
      if (tid >= s) inc += t;
    }
    int total = __shfl(inc, 63, 64);
    histcur[tid] = total - inc;
  }
}

// fused: per-block scan -> cursor, then degree-descending perm + rng
__global__ __launch_bounds__(256) void k_applyperm(
  const int* __restrict__ deg, const int* __restrict__ bbase, int* __restrict__ histcur,
  int* __restrict__ cursor, int* __restrict__ perm, int2* __restrict__ rng)
{
  __shared__ int wsum[4];
  __shared__ int lhist[64];
  __shared__ int lbase[64];
  int tid = threadIdx.x;
  int i = blockIdx.x*256 + tid;
  if (tid < 64) lhist[tid] = 0;
  int v = (i < N_NODES) ? deg[i] : 0;
  int incl = v;
  #pragma unroll
  for (int s = 1; s < 64; s <<= 1){
    int t = __shfl_up(incl, s, 64);
    if ((tid & 63) >= s) incl += t;
  }
  if ((tid & 63) == 63) wsum[tid >> 6] = incl;
  __syncthreads();
  if (tid == 0){ int c = 0; for (int j = 0; j < 4; ++j){ int t = wsum[j]; wsum[j] = c; c += t; } }
  __syncthreads();
  int excl = bbase[blockIdx.x] + wsum[tid >> 6] + (incl - v);
  bool ok = i < N_NODES;
  int b = 0, loc = 0;
  if (ok){
    cursor[i] = excl;
    b = v > 63 ? 63 : v;
    loc = atomicAdd(&lhist[b], 1);
  }
  __syncthreads();
  if (tid < 64){
    int c = lhist[tid];
    lbase[tid] = c ? atomicAdd(&histcur[tid], c) : 0;
  }
  __syncthreads();
  if (ok){
    int pos = lbase[b] + loc;
    perm[pos] = i;
    rng[pos] = make_int2(excl, excl + v);
  }
}

// scatter: (src) + bf16(edge_attr) reordered by dst
__global__ __launch_bounds__(256) void k_scatter(const int* __restrict__ dst, const int* __restrict__ src,
                                                 const float* __restrict__ edge_attr,
                                                 int* __restrict__ cursor,
                                                 int* __restrict__ esrc, ushort* __restrict__ eab){
  int i = blockIdx.x*256 + threadIdx.x;
  if (i < N_EDGES){
    int d = dst[i];
    int pos = atomicAdd(&cursor[d], 1);
    esrc[pos] = src[i];
    const float* ea = edge_attr + (size_t)i*16;
    float4 a = *(const float4*)(ea+0), b = *(const float4*)(ea+4),
           c = *(const float4*)(ea+8), e = *(const float4*)(ea+12);
    uint4 o0, o1;
    o0.x = pkbf(a.x,a.y); o0.y = pkbf(a.z,a.w); o0.z = pkbf(b.x,b.y); o0.w = pkbf(b.z,b.w);
    o1.x = pkbf(c.x,c.y); o1.y = pkbf(c.z,c.w); o1.z = pkbf(e.x,e.y); o1.w = pkbf(e.z,e.w);
    *(uint4*)&eab[(size_t)pos*16]     = o0;
    *(uint4*)&eab[(size_t)pos*16 + 8] = o1;
  }
}

// ---------------- node projections: LN(x) -> q,qWe,k,v,x_r (ALL bf16) ----------------
__global__ __launch_bounds__(256) void k_nodeproj(
  const float* __restrict__ x, const float* __restrict__ lnw, const float* __restrict__ lnb,
  const short* __restrict__ Wtq, const short* __restrict__ Wtqm,
  const short* __restrict__ Wtk, const short* __restrict__ Wtv, const short* __restrict__ Wts,
  const float* __restrict__ bq, const float* __restrict__ bqm,
  const float* __restrict__ bk, const float* __restrict__ bv, const float* __restrict__ bs,
  ushort* __restrict__ qb, ushort* __restrict__ qweb,
  ushort* __restrict__ kb, ushort* __restrict__ vb, ushort* __restrict__ xrb)
{
  __shared__ short A[64][136];
  int tid = threadIdx.x;
  int rbase = blockIdx.x * 64;

  {
    int r = tid >> 2, j = tid & 3;
    int row = rbase + r;
    bool ok = row < N_NODES;
    const float* xp = x + (size_t)row*128 + j*32;
    float vals[32];
    #pragma unroll
    for (int i = 0; i < 8; ++i){
      float4 t = ok ? *(const float4*)(xp + i*4) : make_float4(0,0,0,0);
      vals[i*4+0]=t.x; vals[i*4+1]=t.y; vals[i*4+2]=t.z; vals[i*4+3]=t.w;
    }
    float s = 0.f, s2 = 0.f;
    #pragma unroll
    for (int i = 0; i < 32; ++i){ s += vals[i]; s2 += vals[i]*vals[i]; }
    s  += __shfl_xor(s, 1, 64);  s  += __shfl_xor(s, 2, 64);
    s2 += __shfl_xor(s2, 1, 64); s2 += __shfl_xor(s2, 2, 64);
    float mean = s * 0.0078125f;
    float var  = s2 * 0.0078125f - mean*mean;
    float rstd = rsqrtf(var + 1e-5f);
    #pragma unroll
    for (int i = 0; i < 32; ++i){
      int col = j*32 + i;
      float xn = (vals[i]-mean)*rstd*lnw[col] + lnb[col];
      A[r][col] = f2bf(xn);
    }
  }
  __syncthreads();

  int lane = tid & 63, wave = tid >> 6;
  int row16 = lane & 15, kg = lane >> 4;
  int cb = wave * 32;

  auto gemm = [&](const short* __restrict__ B, const float* __restrict__ bias,
                  ushort* __restrict__ Ob){
    f32x4 acc[4][2] = {};
    #pragma unroll
    for (int kk = 0; kk < 128; kk += 32){
      int k0 = kk + kg*8;
      bf16x8 a0 = *(const bf16x8*)&A[ 0 + row16][k0];
      bf16x8 a1 = *(const bf16x8*)&A[16 + row16][k0];
      bf16x8 a2 = *(const bf16x8*)&A[32 + row16][k0];
      bf16x8 a3 = *(const bf16x8*)&A[48 + row16][k0];
      bf16x8 b0 = *(const bf16x8*)&B[(size_t)(cb +      row16)*128 + k0];
      bf16x8 b1 = *(const bf16x8*)&B[(size_t)(cb + 16 + row16)*128 + k0];
      acc[0][0] = __builtin_amdgcn_mfma_f32_16x16x32_bf16(a0, b0, acc[0][0], 0,0,0);
      acc[1][0] = __builtin_amdgcn_mfma_f32_16x16x32_bf16(a1, b0, acc[1][0], 0,0,0);
      acc[2][0] = __builtin_amdgcn_mfma_f32_16x16x32_bf16(a2, b0, acc[2][0], 0,0,0);
      acc[3][0] = __builtin_amdgcn_mfma_f32_16x16x32_bf16(a3, b0, acc[3][0], 0,0,0);
      acc[0][1] = __builtin_amdgcn_mfma_f32_16x16x32_bf16(a0, b1, acc[0][1], 0,0,0);
      acc[1][1] = __builtin_amdgcn_mfma_f32_16x16x32_bf16(a1, b1, acc[1][1], 0,0,0);
      acc[2][1] = __builtin_amdgcn_mfma_f32_16x16x32_bf16(a2, b1, acc[2][1], 0,0,0);
      acc[3][1] = __builtin_amdgcn_mfma_f32_16x16x32_bf16(a3, b1, acc[3][1], 0,0,0);
    }
    float bv0 = bias[cb + row16], bv1 = bias[cb + 16 + row16];
    #pragma unroll
    for (int rt = 0; rt < 4; ++rt){
      #pragma unroll
      for (int i = 0; i < 4; ++i){
        int row = rbase + rt*16 + kg*4 + i;
        if (row < N_NODES){
          Ob[(size_t)row*128 + cb      + row16] = (ushort)f2bf(acc[rt][0][i] + bv0);
          Ob[(size_t)row*128 + cb + 16 + row16] = (ushort)f2bf(acc[rt][1][i] + bv1);
        }
      }
    }
  };
  gemm(Wtq,  bq,  qb);
  gemm(Wtqm, bqm, qweb);
  gemm(Wtk,  bk,  kb);
  gemm(Wtv,  bv,  vb);
  gemm(Wts,  bs,  xrb);
}

// ---------------- edge attention aggregation: 2 nodes/wave, degree-sorted, pipelined ----------------
__global__ __launch_bounds__(256) void k_agg(
  const ushort* __restrict__ qb, const ushort* __restrict__ qweb,
  const ushort* __restrict__ kbf, const ushort* __restrict__ vbf,
  const ushort* __restrict__ eab, const float* __restrict__ We, const float* __restrict__ be,
  const int* __restrict__ esrc, const int* __restrict__ perm, const int2* __restrict__ rng,
  ushort* __restrict__ xrb)
{
  int tid = threadIdx.x;
  int gid = blockIdx.x*8 + (tid >> 5);
  int node = perm[gid];
  int2 r = rng[gid];
  int beg = r.x, end = r.y;
  int l = tid & 31;
  int d0 = l*4;
  int h  = l >> 2;
  int c0 = (l & 3)*4;

  uint2 qw = *(const uint2*)&qb[(size_t)node*128 + d0];
  float4 qv = make_float4(BF_LO(qw.x), BF_HI(qw.x), BF_LO(qw.y), BF_HI(qw.y));
  uint2 qew = *(const uint2*)&qweb[(size_t)node*128 + h*16 + c0];
  float4 qe = make_float4(BF_LO(qew.x), BF_HI(qew.x), BF_LO(qew.y), BF_HI(qew.y));
  float m = -INFINITY, den = 0.f;
  float4 va = make_float4(0,0,0,0);
  float4 S  = make_float4(0,0,0,0);

  int p = beg;

  // main loop: unroll 8 with next-batch index prefetch
  int s8[8];
  {
    bool have = (beg + 8 <= end);
    #pragma unroll
    for (int j = 0; j < 8; ++j) s8[j] = have ? esrc[beg + j] : 0;
  }
  for (; p + 8 <= end; p += 8){
    int n8[8];
    bool more = (p + 16 <= end);
    #pragma unroll
    for (int j = 0; j < 8; ++j) n8[j] = more ? esrc[p + 8 + j] : 0;
    uint2 kw[8], vw[8], ew[8];
    #pragma unroll
    for (int j = 0; j < 8; ++j){
      kw[j] = *(const uint2*)&kbf[(size_t)s8[j]*128 + d0];
      vw[j] = *(const uint2*)&vbf[(size_t)s8[j]*128 + d0];
      ew[j] = *(const uint2*)&eab[(size_t)(p+j)*16 + c0];
    }
    float sc[8];
    #pragma unroll
    for (int j = 0; j < 8; ++j){
      float pp = qv.x*BF_LO(kw[j].x) + qv.y*BF_HI(kw[j].x)
               + qv.z*BF_LO(kw[j].y) + qv.w*BF_HI(kw[j].y)
               + qe.x*BF_LO(ew[j].x) + qe.y*BF_HI(ew[j].x)
               + qe.z*BF_LO(ew[j].y) + qe.w*BF_HI(ew[j].y);
      pp += __shfl_xor(pp,1,64); pp += __shfl_xor(pp,2,64);
      sc[j] = pp*0.25f;
    }
    float mn = m;
    #pragma unroll
    for (int j = 0; j < 8; ++j) mn = fmaxf(mn, sc[j]);
    float corr = __expf(m - mn);
    float w[8]; float ds = 0.f;
    #pragma unroll
    for (int j = 0; j < 8; ++j){ w[j] = __expf(sc[j]-mn); ds += w[j]; }
    den = den*corr + ds;
    float ax=0.f, ay=0.f, az=0.f, aw2=0.f, sx=0.f, sy=0.f, sz=0.f, sw=0.f;
    #pragma unroll
    for (int j = 0; j < 8; ++j){
      ax += w[j]*BF_LO(vw[j].x); ay += w[j]*BF_HI(vw[j].x);
      az += w[j]*BF_LO(vw[j].y); aw2+= w[j]*BF_HI(vw[j].y);
      sx += w[j]*BF_LO(ew[j].x); sy += w[j]*BF_HI(ew[j].x);
      sz += w[j]*BF_LO(ew[j].y); sw += w[j]*BF_HI(ew[j].y);
    }
    va.x = va.x*corr + ax; va.y = va.y*corr + ay;
    va.z = va.z*corr + az; va.w = va.w*corr + aw2;
    S.x  = S.x *corr + sx; S.y  = S.y *corr + sy;
    S.z  = S.z *corr + sz; S.w  = S.w *corr + sw;
    m = mn;
    #pragma unroll
    for (int j = 0; j < 8; ++j) s8[j] = n8[j];
  }

#define AGG_STEP(J)                                                            \
  {                                                                            \
    int sidx[J];                                                               \
    _Pragma("unroll")                                                          \
    for (int j = 0; j < J; ++j) sidx[j] = esrc[p+j];                           \
    uint2 kw[J], vw[J], ew[J];                                                 \
    _Pragma("unroll")                                                          \
    for (int j = 0; j < J; ++j){                                               \
      kw[j] = *(const uint2*)&kbf[(size_t)sidx[j]*128 + d0];                   \
      vw[j] = *(const uint2*)&vbf[(size_t)sidx[j]*128 + d0];                   \
      ew[j] = *(const uint2*)&eab[(size_t)(p+j)*16 + c0];                      \
    }                                                                          \
    float sc[J];                                                               \
    _Pragma("unroll")                                                          \
    for (int j = 0; j < J; ++j){                                               \
      float pp = qv.x*BF_LO(kw[j].x) + qv.y*BF_HI(kw[j].x)                     \
               + qv.z*BF_LO(kw[j].y) + qv.w*BF_HI(kw[j].y)                     \
               + qe.x*BF_LO(ew[j].x) + qe.y*BF_HI(ew[j].x)                     \
               + qe.z*BF_LO(ew[j].y) + qe.w*BF_HI(ew[j].y);                    \
      pp += __shfl_xor(pp,1,64); pp += __shfl_xor(pp,2,64);                    \
      sc[j] = pp*0.25f;                                                        \
    }                                                                          \
    float mn = m;                                                              \
    _Pragma("unroll")                                                          \
    for (int j = 0; j < J; ++j) mn = fmaxf(mn, sc[j]);                         \
    float corr = __expf(m - mn);                                               \
    float w[J]; float ds = 0.f;                                                \
    _Pragma("unroll")                                                          \
    for (int j = 0; j < J; ++j){ w[j] = __expf(sc[j]-mn); ds += w[j]; }        \
    den = den*corr + ds;                                                       \
    float ax=0.f, ay=0.f, az=0.f, aw2=0.f, sx=0.f, sy=0.f, sz=0.f, sw=0.f;     \
    _Pragma("unroll")                                                          \
    for (int j = 0; j < J; ++j){                                               \
      ax += w[j]*BF_LO(vw[j].x); ay += w[j]*BF_HI(vw[j].x);                    \
      az += w[j]*BF_LO(vw[j].y); aw2+= w[j]*BF_HI(vw[j].y);                    \
      sx += w[j]*BF_LO(ew[j].x); sy += w[j]*BF_HI(ew[j].x);                    \
      sz += w[j]*BF_LO(ew[j].y); sw += w[j]*BF_HI(ew[j].y);                    \
    }                                                                          \
    va.x = va.x*corr + ax; va.y = va.y*corr + ay;                              \
    va.z = va.z*corr + az; va.w = va.w*corr + aw2;                             \
    S.x  = S.x *corr + sx; S.y  = S.y *corr + sy;                              \
    S.z  = S.z *corr + sz; S.w  = S.w *corr + sw;                              \
    m = mn;                                                                    \
  }

  for (; p + 4 <= end; p += 4) AGG_STEP(4)
  for (; p < end; ++p){
    int s = esrc[p];
    uint2 kw = *(const uint2*)&kbf[(size_t)s*128 + d0];
    uint2 vw = *(const uint2*)&vbf[(size_t)s*128 + d0];
    uint2 ew = *(const uint2*)&eab[(size_t)p*16 + c0];
    float pp = qv.x*BF_LO(kw.x) + qv.y*BF_HI(kw.x)
             + qv.z*BF_LO(kw.y) + qv.w*BF_HI(kw.y)
             + qe.x*BF_LO(ew.x) + qe.y*BF_HI(ew.x)
             + qe.z*BF_LO(ew.y) + qe.w*BF_HI(ew.y);
    pp += __shfl_xor(pp,1,64); pp += __shfl_xor(pp,2,64);
    float sc = pp*0.25f;
    float mn = fmaxf(m, sc);
    float corr = __expf(m - mn);
    float pe = __expf(sc - mn);
    den = den*corr + pe;
    va.x = va.x*corr + pe*BF_LO(vw.x);
    va.y = va.y*corr + pe*BF_HI(vw.x);
    va.z = va.z*corr + pe*BF_LO(vw.y);
    va.w = va.w*corr + pe*BF_HI(vw.y);
    S.x = S.x*corr + pe*BF_LO(ew.x);
    S.y = S.y*corr + pe*BF_HI(ew.x);
    S.z = S.z*corr + pe*BF_LO(ew.y);
    S.w = S.w*corr + pe*BF_HI(ew.y);
    m = mn;
  }

  if (end > beg){
    float inv = 1.0f/den;
    float4 acc = va;
    int gb = (tid & 63) & 60;
    #pragma unroll
    for (int g = 0; g < 4; ++g){
      float s0 = __shfl(S.x, gb+g, 64);
      float s1 = __shfl(S.y, gb+g, 64);
      float s2 = __shfl(S.z, gb+g, 64);
      float s3 = __shfl(S.w, gb+g, 64);
      float4 w0 = *(const float4*)&We[(g*4+0)*128 + d0];
      float4 w1 = *(const float4*)&We[(g*4+1)*128 + d0];
      float4 w2 = *(const float4*)&We[(g*4+2)*128 + d0];
      float4 w3 = *(const float4*)&We[(g*4+3)*128 + d0];
      acc.x += s0*w0.x + s1*w1.x + s2*w2.x + s3*w3.x;
      acc.y += s0*w0.y + s1*w1.y + s2*w2.y + s3*w3.y;
      acc.z += s0*w0.z + s1*w1.z + s2*w2.z + s3*w3.z;
      acc.w += s0*w0.w + s1*w1.w + s2*w2.w + s3*w3.w;
    }
    float4 bev = *(const float4*)&be[d0];
    uint2 xw = *(const uint2*)&xrb[(size_t)node*128 + d0];
    float4 xv = make_float4(BF_LO(xw.x), BF_HI(xw.x), BF_LO(xw.y), BF_HI(xw.y));
    xv.x += acc.x*inv + bev.x;
    xv.y += acc.y*inv + bev.y;
    xv.z += acc.z*inv + bev.z;
    xv.w += acc.w*inv + bev.w;
    uint2 ow;
    ow.x = pkbf(xv.x, xv.y);
    ow.y = pkbf(xv.z, xv.w);
    *(uint2*)&xrb[(size_t)node*128 + d0] = ow;
  }
}

// ---------------- fused post+MLP: rf in REGISTERS (+bf16 LDS copy for LN); hidden 2x256 ----------------
__global__ __launch_bounds__(256) void k_postmlp(
  const ushort* __restrict__ aggout, const float* __restrict__ x,
  const short* __restrict__ Wtp, const float* __restrict__ bp,
  const float* __restrict__ lnw, const float* __restrict__ lnb,
  const short* __restrict__ W1t, const float* __restrict__ b1,
  const short* __restrict__ W2t, const float* __restrict__ b2,
  float* __restrict__ out)
{
  __shared__ short A[32][136];
  __shared__ short rfb[32][136];
  __shared__ short Hd[32][264];
  int tid = threadIdx.x;
  int rbase = blockIdx.x * 32;
  int lane = tid & 63, wave = tid >> 6;
  int row16 = lane & 15, kg = lane >> 4;
  int cb = wave * 32;

  // prefetch x residual into registers (mapping matches phase-1 output)
  float rfreg[2][2][4];
  #pragma unroll
  for (int rt = 0; rt < 2; ++rt){
    #pragma unroll
    for (int i = 0; i < 4; ++i){
      int row = rbase + rt*16 + kg*4 + i;
      bool ok = row < N_NODES;
      rfreg[rt][0][i] = ok ? x[(size_t)row*128 + cb      + row16] : 0.f;
      rfreg[rt][1][i] = ok ? x[(size_t)row*128 + cb + 16 + row16] : 0.f;
    }
  }

  // phase 0: load bf16 aggout tile
  for (int idx = tid; idx < 512; idx += 256){
    int r = idx >> 4, g = idx & 15;
    *(uint4*)&A[r][g*8] = *(const uint4*)&aggout[((size_t)(rbase + r))*128 + g*8];
  }
  __syncthreads();

  // phase 1: rfreg += A@Wtp + bp ; write bf16 copy to rfb for LN
  {
    f32x4 acc[2][2] = {};
    #pragma unroll
    for (int kk = 0; kk < 128; kk += 32){
      int k0 = kk + kg*8;
      bf16x8 a0 = *(const bf16x8*)&A[     row16][k0];
      bf16x8 a1 = *(const bf16x8*)&A[16 + row16][k0];
      bf16x8 b0 = *(const bf16x8*)&Wtp[(size_t)(cb +      row16)*128 + k0];
      bf16x8 b1 = *(const bf16x8*)&Wtp[(size_t)(cb + 16 + row16)*128 + k0];
      acc[0][0] = __builtin_amdgcn_mfma_f32_16x16x32_bf16(a0, b0, acc[0][0], 0,0,0);
      acc[1][0] = __builtin_amdgcn_mfma_f32_16x16x32_bf16(a1, b0, acc[1][0], 0,0,0);
      acc[0][1] = __builtin_amdgcn_mfma_f32_16x16x32_bf16(a0, b1, acc[0][1], 0,0,0);
      acc[1][1] = __builtin_amdgcn_mfma_f32_16x16x32_bf16(a1, b1, acc[1][1], 0,0,0);
    }
    float bv0 = bp[cb + row16], bv1 = bp[cb + 16 + row16];
    #pragma unroll
    for (int rt = 0; rt < 2; ++rt){
      #pragma unroll
      for (int i = 0; i < 4; ++i){
        int rl = rt*16 + kg*4 + i;
        float v0 = rfreg[rt][0][i] + acc[rt][0][i] + bv0;
        float v1 = rfreg[rt][1][i] + acc[rt][1][i] + bv1;
        rfreg[rt][0][i] = v0;
        rfreg[rt][1][i] = v1;
        rfb[rl][cb      + row16] = f2bf(v0);
        rfb[rl][cb + 16 + row16] = f2bf(v1);
      }
    }
  }
  __syncthreads();

  // phase 2: LN(rfb) -> A (bf16); 8 threads/row, 16 cols each
  {
    int r = tid >> 3, j = tid & 7;
    uint4 t0 = *(const uint4*)&rfb[r][j*16];
    uint4 t1 = *(const uint4*)&rfb[r][j*16 + 8];
    unsigned u[8] = {t0.x,t0.y,t0.z,t0.w, t1.x,t1.y,t1.z,t1.w};
    float vals[16];
    #pragma unroll
    for (int i = 0; i < 8; ++i){ vals[2*i] = BF_LO(u[i]); vals[2*i+1] = BF_HI(u[i]); }
    float s = 0.f, s2 = 0.f;
    #pragma unroll
    for (int i = 0; i < 16; ++i){ s += vals[i]; s2 += vals[i]*vals[i]; }
    s  += __shfl_xor(s, 1, 64);  s  += __shfl_xor(s, 2, 64);  s  += __shfl_xor(s, 4, 64);
    s2 += __shfl_xor(s2, 1, 64); s2 += __shfl_xor(s2, 2, 64); s2 += __shfl_xor(s2, 4, 64);
    float mean = s * 0.0078125f;
    float var  = s2 * 0.0078125f - mean*mean;
    float rstd = rsqrtf(var + 1e-5f);
    #pragma unroll
    for (int i = 0; i < 16; ++i){
      int col = j*16 + i;
      A[r][col] = f2bf((vals[i]-mean)*rstd*lnw[col] + lnb[col]);
    }
  }

  // phases 3/4: hidden split into two 256-col halves; acc2 persists across halves
  f32x4 acc2[2][2] = {};
  #pragma unroll
  for (int half = 0; half < 2; ++half){
    __syncthreads();   // half 0: A ready; half 1: protect Hd from phase-4 readers
    // phase 3: Hd = bf16(gelu(A@W1half + b1half)); each wave 64 cols
    {
      f32x4 acc[2][4] = {};
      #pragma unroll
      for (int kk = 0; kk < 128; kk += 32){
        int k0 = kk + kg*8;
        bf16x8 a0 = *(const bf16x8*)&A[     row16][k0];
        bf16x8 a1 = *(const bf16x8*)&A[16 + row16][k0];
        #pragma unroll
        for (int ct = 0; ct < 4; ++ct){
          bf16x8 b = *(const bf16x8*)&W1t[(size_t)(half*256 + wave*64 + ct*16 + row16)*128 + k0];
          acc[0][ct] = __builtin_amdgcn_mfma_f32_16x16x32_bf16(a0, b, acc[0][ct], 0,0,0);
          acc[1][ct] = __builtin_amdgcn_mfma_f32_16x16x32_bf16(a1, b, acc[1][ct], 0,0,0);
        }
      }
      #pragma unroll
      for (int ct = 0; ct < 4; ++ct){
        int col = wave*64 + ct*16 + row16;       // local 0..255
        float bb = b1[half*256 + col];
        #pragma unroll
        for (int rt = 0; rt < 2; ++rt)
          #pragma unroll
          for (int i = 0; i < 4; ++i)
            Hd[rt*16 + kg*4 + i][col] = f2bf(gelu_f(acc[rt][ct][i] + bb));
      }
    }
    __syncthreads();
    // phase 4 partial: acc2 += Hd @ W2half; each wave 32 out cols, K=256
    {
      #pragma unroll
      for (int kc = 0; kc < 8; ++kc){
        int k0 = kc*32 + kg*8;                   // local 0..255
        bf16x8 a0 = *(const bf16x8*)&Hd[     row16][k0];
        bf16x8 a1 = *(const bf16x8*)&Hd[16 + row16][k0];
        bf16x8 b0 = *(const bf16x8*)&W2t[(size_t)(cb +      row16)*512 + half*256 + k0];
        bf16x8 b1 = *(const bf16x8*)&W2t[(size_t)(cb + 16 + row16)*512 + half*256 + k0];
        acc2[0][0] = __builtin_amdgcn_mfma_f32_16x16x32_bf16(a0, b0, acc2[0][0], 0,0,0);
        acc2[1][0] = __builtin_amdgcn_mfma_f32_16x16x32_bf16(a1, b0, acc2[1][0], 0,0,0);
        acc2[0][1] = __builtin_amdgcn_mfma_f32_16x16x32_bf16(a0, b1, acc2[0][1], 0,0,0);
        acc2[1][1] = __builtin_amdgcn_mfma_f32_16x16x32_bf16(a1, b1, acc2[1][1], 0,0,0);
      }
    }
  }

  // epilogue: out = acc2 + b2 + rfreg (f32 registers)
  {
    float bv0 = b2[cb + row16], bv1 = b2[cb + 16 + row16];
    #pragma unroll
    for (int rt = 0; rt < 2; ++rt){
      #pragma unroll
      for (int i = 0; i < 4; ++i){
        int row = rbase + rt*16 + kg*4 + i;
        if (row < N_NODES){
          out[(size_t)row*128 + cb      + row16] = acc2[rt][0][i] + bv0 + rfreg[rt][0][i];
          out[(size_t)row*128 + cb + 16 + row16] = acc2[rt][1][i] + bv1 + rfreg[rt][1][i];
        }
      }
    }
  }
}

extern "C" void kernel_launch(void* const* d_in, const int* in_sizes, int n_in,
                              void* d_out, int out_size, void* d_ws, size_t ws_size,
                              hipStream_t stream)
{
  const float* x        = (const float*)d_in[0];
  const float* edge_attr= (const float*)d_in[1];
  const int*   edge_index=(const int*)d_in[2];
  const float* Wq = (const float*)d_in[3];  const float* bq = (const float*)d_in[4];
  const float* Wk = (const float*)d_in[5];  const float* bk = (const float*)d_in[6];
  const float* Wv = (const float*)d_in[7];  const float* bv = (const float*)d_in[8];
  const float* Wss= (const float*)d_in[9];  const float* bss= (const float*)d_in[10];
  const float* We = (const float*)d_in[11]; const float* be = (const float*)d_in[12];
  const float* Wp = (const float*)d_in[13]; const float* bp = (const float*)d_in[14];
  const float* lnaw=(const float*)d_in[15]; const float* lnab=(const float*)d_in[16];
  const float* lnmw=(const float*)d_in[17]; const float* lnmb=(const float*)d_in[18];
  const float* W1 = (const float*)d_in[19]; const float* b1 = (const float*)d_in[20];
  const float* W2 = (const float*)d_in[21]; const float* b2 = (const float*)d_in[22];

  float* ws = (float*)d_ws;
  // N_PAD = 50048 rows; bf16 [NP][128] = NPH float units
  const size_t NPH = 3203072;
  ushort* qb   = (ushort*)ws;
  ushort* qweb = (ushort*)(ws + NPH);
  ushort* kbf  = (ushort*)(ws + 2*NPH);
  ushort* vbf  = (ushort*)(ws + 3*NPH);
  ushort* xrb  = (ushort*)(ws + 4*NPH);
  ushort* eab  = (ushort*)(ws + 5*NPH);        // bf16 [E][16]
  short* wts   = (short*)(ws + 25624576);
  short* Wtq   = wts;
  short* Wtk   = wts + 16384;
  short* Wtv   = wts + 32768;
  short* Wts_  = wts + 49152;
  short* Wtp   = wts + 65536;
  short* Wtqm  = wts + 81920;
  short* W1t   = wts + 98304;                  // [512][128]
  short* W2t   = wts + 163840;                 // [128][512]
  float* bqm   = ws + 25624576 + 114688 + 16384;
  int*   iw    = (int*)(bqm + 128);
  int* deg     = iw;                           // 50000
  int* hist    = iw + 50000;                   // 64
  int* histcur = iw + 50064;                   // 64
  int* bsum    = iw + 50128;                   // 196
  int* bbase   = iw + 50324;                   // 196
  int* cursor  = iw + 50520;                   // 50000
  int* perm    = iw + 100520;                  // 50000
  int2* rng    = (int2*)(iw + 150520);         // 50000 pairs (even offset)
  int* esrc    = iw + 250520;                  // 800000

  const int* srcIdx = edge_index;
  const int* dstIdx = edge_index + N_EDGES;

  // unified weight prep (single launch)
  Prep pa;
  pa.src[0]=Wq; pa.src[1]=Wk; pa.src[2]=Wv; pa.src[3]=Wss; pa.src[4]=Wp;
  pa.dst[0]=Wtq; pa.dst[1]=Wtk; pa.dst[2]=Wtv; pa.dst[3]=Wts_; pa.dst[4]=Wtp;
  pa.Wq=Wq; pa.We=We; pa.bq=bq; pa.Wtqm=Wtqm; pa.bqm=bqm;
  pa.W1=W1; pa.W1t=W1t; pa.W2=W2; pa.W2t=W2t;
  k_prep<<<896, 256, 0, stream>>>(pa);

  // CSR + degree-sort
  hipMemsetAsync(deg, 0, 50064*sizeof(int), stream);   // deg + hist
  k_deg<<<(N_EDGES+255)/256, 256, 0, stream>>>(dstIdx, edge_attr, deg,
                                               (float*)d_out + (size_t)N_NODES*128);
  k_bsum<<<196, 256, 0, stream>>>(deg, bsum, hist);
  k_bscan<<<1, 256, 0, stream>>>(bsum, bbase, hist, histcur);
  k_applyperm<<<196, 256, 0, stream>>>(deg, bbase, histcur, cursor, perm, rng);
  k_scatter<<<(N_EDGES+255)/256, 256, 0, stream>>>(dstIdx, srcIdx, edge_attr, cursor, esrc, eab);

  // main pipeline
  k_nodeproj<<<782, 256, 0, stream>>>(x, lnaw, lnab, Wtq, Wtqm, Wtk, Wtv, Wts_,
                                      bq, bqm, bk, bv, bss, qb, qweb, kbf, vbf, xrb);
  k_agg<<<N_NODES/8, 256, 0, stream>>>(qb, qweb, kbf, vbf, eab, We, be,
                                       esrc, perm, rng, xrb);
  k_postmlp<<<1564, 256, 0, stream>>>(xrb, x, Wtp, bp, lnmw, lnmb,
                                      W1t, b1, W2t, b2, (float*)d_out);
}

// Round 15
// 311.457 us; speedup vs baseline: 1.0560x; 1.0560x over previous
//
#include <hip/hip_runtime.h>
#include <math.h>

#define N_NODES 50000
#define N_EDGES 800000

typedef __attribute__((ext_vector_type(8))) short bf16x8;
typedef __attribute__((ext_vector_type(4))) float f32x4;

__device__ __forceinline__ short f2bf(float f){
  unsigned u = __float_as_uint(f);
  unsigned r = (u + 0x7FFFu + ((u >> 16) & 1u)) >> 16;
  return (short)r;
}
__device__ __forceinline__ unsigned pkbf(float lo, float hi){
  return (unsigned)(unsigned short)f2bf(lo) | ((unsigned)(unsigned short)f2bf(hi) << 16);
}

__device__ __forceinline__ float gelu_f(float x){
  float z = 0.7978845608028654f*(x + 0.044715f*x*x*x);
  float e = __expf(2.0f*z);
  return 0.5f*x*(2.0f - 2.0f/(e + 1.0f));   // 0.5x(1+tanh z), inf-safe
}

#define BF_LO(u) __uint_as_float((u)<<16)
#define BF_HI(u) __uint_as_float((u)&0xffff0000u)

// ---------------- unified weight prep: 5 transposes + Wqm fold + W1t + W2t ----------------
struct Prep {
  const float* src[5]; short* dst[5];
  const float* Wq; const float* We; const float* bq;
  short* Wtqm; float* bqm;
  const float* W1; short* W1t;
  const float* W2; short* W2t;
};
__global__ __launch_bounds__(256) void k_prep(Prep a){
  int blk = blockIdx.x, tid = threadIdx.x;
  if (blk < 320){
    int b = blk >> 6;
    int i = (blk & 63)*256 + tid;
    int n = i >> 7, k = i & 127;
    a.dst[b][n*128 + k] = f2bf(a.src[b][k*128 + n]);
  } else if (blk < 384){
    int i = (blk - 320)*256 + tid;
    int k = i >> 7, j = i & 127;
    int h = j >> 4, c = j & 15;
    float s = 0.f;
    #pragma unroll
    for (int dd = 0; dd < 16; ++dd)
      s += a.Wq[k*128 + h*16 + dd] * a.We[c*128 + h*16 + dd];
    a.Wtqm[j*128 + k] = f2bf(s);
    if (k == 0){
      float t = 0.f;
      #pragma unroll
      for (int dd = 0; dd < 16; ++dd)
        t += a.bq[h*16 + dd] * a.We[c*128 + h*16 + dd];
      a.bqm[j] = t;
    }
  } else if (blk < 640){
    int i = (blk - 384)*256 + tid;   // W1t [512][128] <- W1 [128][512]
    int n = i >> 7, k = i & 127;
    a.W1t[n*128 + k] = f2bf(a.W1[k*512 + n]);
  } else {
    int i = (blk - 640)*256 + tid;   // W2t [128][512] <- W2 [512][128]
    int n = i >> 9, k = i & 511;
    a.W2t[n*512 + k] = f2bf(a.W2[k*128 + n]);
  }
}

// ---------------- CSR build ----------------
__global__ __launch_bounds__(256) void k_deg(const int* __restrict__ dst, int* __restrict__ deg){
  int i = blockIdx.x*256 + threadIdx.x;
  if (i < N_EDGES) atomicAdd(&deg[dst[i]], 1);
}

__global__ __launch_bounds__(256) void k_bsum(const int* __restrict__ deg,
                                              int* __restrict__ bsum, int* __restrict__ hist){
  __shared__ int lhist[64];
  __shared__ int wred[4];
  int tid = threadIdx.x;
  int i = blockIdx.x*256 + tid;
  if (tid < 64) lhist[tid] = 0;
  __syncthreads();
  int v = (i < N_NODES) ? deg[i] : 0;
  if (i < N_NODES) atomicAdd(&lhist[v > 63 ? 63 : v], 1);
  int s = v;
  #pragma unroll
  for (int sh = 32; sh >= 1; sh >>= 1) s += __shfl_xor(s, sh, 64);
  if ((tid & 63) == 0) wred[tid >> 6] = s;
  __syncthreads();
  if (tid == 0) bsum[blockIdx.x] = wred[0] + wred[1] + wred[2] + wred[3];
  if (tid < 64){ int c = lhist[tid]; if (c) atomicAdd(&hist[tid], c); }
}

__global__ __launch_bounds__(256) void k_bscan(const int* __restrict__ bsum, int* __restrict__ bbase,
                                               const int* __restrict__ hist, int* __restrict__ histcur){
  __shared__ int wsum[4];
  int tid = threadIdx.x;
  int v = (tid < 196) ? bsum[tid] : 0;
  int incl = v;
  #pragma unroll
  for (int s = 1; s < 64; s <<= 1){
    int t = __shfl_up(incl, s, 64);
    if ((tid & 63) >= s) incl += t;
  }
  if ((tid & 63) == 63) wsum[tid >> 6] = incl;
  __syncthreads();
  if (tid == 0){ int c = 0; for (int j = 0; j < 4; ++j){ int t = wsum[j]; wsum[j] = c; c += t; } }
  __syncthreads();
  if (tid < 196) bbase[tid] = wsum[tid >> 6] + (incl - v);
  if (tid < 64){
    int h = hist[tid];
    int inc = h;
    #pragma unroll
    for (int s = 1; s < 64; s <<= 1){
      int t = __shfl_up(inc, s, 64);
      if (tid >= s) inc += t;
    }
    int total = __shfl(inc, 63, 64);
    histcur[tid] = total - inc;
  }
}

// fused: per-block scan -> cursor, then degree-descending perm + rng
__global__ __launch_bounds__(256) void k_applyperm(
  const int* __restrict__ deg, const int* __restrict__ bbase, int* __restrict__ histcur,
  int* __restrict__ cursor, int* __restrict__ perm, int2* __restrict__ rng)
{
  __shared__ int wsum[4];
  __shared__ int lhist[64];
  __shared__ int lbase[64];
  int tid = threadIdx.x;
  int i = blockIdx.x*256 + tid;
  if (tid < 64) lhist[tid] = 0;
  int v = (i < N_NODES) ? deg[i] : 0;
  int incl = v;
  #pragma unroll
  for (int s = 1; s < 64; s <<= 1){
    int t = __shfl_up(incl, s, 64);
    if ((tid & 63) >= s) incl += t;
  }
  if ((tid & 63) == 63) wsum[tid >> 6] = incl;
  __syncthreads();
  if (tid == 0){ int c = 0; for (int j = 0; j < 4; ++j){ int t = wsum[j]; wsum[j] = c; c += t; } }
  __syncthreads();
  int excl = bbase[blockIdx.x] + wsum[tid >> 6] + (incl - v);
  bool ok = i < N_NODES;
  int b = 0, loc = 0;
  if (ok){
    cursor[i] = excl;
    b = v > 63 ? 63 : v;
    loc = atomicAdd(&lhist[b], 1);
  }
  __syncthreads();
  if (tid < 64){
    int c = lhist[tid];
    lbase[tid] = c ? atomicAdd(&histcur[tid], c) : 0;
  }
  __syncthreads();
  if (ok){
    int pos = lbase[b] + loc;
    perm[pos] = i;
    rng[pos] = make_int2(excl, excl + v);
  }
}

// scatter: (src) + bf16(edge_attr) reordered by dst; also passthrough copy -> out
__global__ __launch_bounds__(256) void k_scatter(const int* __restrict__ dst, const int* __restrict__ src,
                                                 const float* __restrict__ edge_attr,
                                                 int* __restrict__ cursor,
                                                 int* __restrict__ esrc, ushort* __restrict__ eab,
                                                 float* __restrict__ eout){
  int i = blockIdx.x*256 + threadIdx.x;
  if (i < N_EDGES){
    int d = dst[i];
    int pos = atomicAdd(&cursor[d], 1);
    esrc[pos] = src[i];
    const float* ea = edge_attr + (size_t)i*16;
    float4 a = *(const float4*)(ea+0), b = *(const float4*)(ea+4),
           c = *(const float4*)(ea+8), e = *(const float4*)(ea+12);
    uint4 o0, o1;
    o0.x = pkbf(a.x,a.y); o0.y = pkbf(a.z,a.w); o0.z = pkbf(b.x,b.y); o0.w = pkbf(b.z,b.w);
    o1.x = pkbf(c.x,c.y); o1.y = pkbf(c.z,c.w); o1.z = pkbf(e.x,e.y); o1.w = pkbf(e.z,e.w);
    *(uint4*)&eab[(size_t)pos*16]     = o0;
    *(uint4*)&eab[(size_t)pos*16 + 8] = o1;
    float* op = eout + (size_t)i*16;
    *(float4*)(op+0)  = a;
    *(float4*)(op+4)  = b;
    *(float4*)(op+8)  = c;
    *(float4*)(op+12) = e;
  }
}

// ---------------- node projections: LN(x) -> q,qWe,k,v,x_r (ALL bf16) ----------------
__global__ __launch_bounds__(256) void k_nodeproj(
  const float* __restrict__ x, const float* __restrict__ lnw, const float* __restrict__ lnb,
  const short* __restrict__ Wtq, const short* __restrict__ Wtqm,
  const short* __restrict__ Wtk, const short* __restrict__ Wtv, const short* __restrict__ Wts,
  const float* __restrict__ bq, const float* __restrict__ bqm,
  const float* __restrict__ bk, const float* __restrict__ bv, const float* __restrict__ bs,
  ushort* __restrict__ qb, ushort* __restrict__ qweb,
  ushort* __restrict__ kb, ushort* __restrict__ vb, ushort* __restrict__ xrb)
{
  __shared__ short A[64][136];
  int tid = threadIdx.x;
  int rbase = blockIdx.x * 64;

  {
    int r = tid >> 2, j = tid & 3;
    int row = rbase + r;
    bool ok = row < N_NODES;
    const float* xp = x + (size_t)row*128 + j*32;
    float vals[32];
    #pragma unroll
    for (int i = 0; i < 8; ++i){
      float4 t = ok ? *(const float4*)(xp + i*4) : make_float4(0,0,0,0);
      vals[i*4+0]=t.x; vals[i*4+1]=t.y; vals[i*4+2]=t.z; vals[i*4+3]=t.w;
    }
    float s = 0.f, s2 = 0.f;
    #pragma unroll
    for (int i = 0; i < 32; ++i){ s += vals[i]; s2 += vals[i]*vals[i]; }
    s  += __shfl_xor(s, 1, 64);  s  += __shfl_xor(s, 2, 64);
    s2 += __shfl_xor(s2, 1, 64); s2 += __shfl_xor(s2, 2, 64);
    float mean = s * 0.0078125f;
    float var  = s2 * 0.0078125f - mean*mean;
    float rstd = rsqrtf(var + 1e-5f);
    #pragma unroll
    for (int i = 0; i < 32; ++i){
      int col = j*32 + i;
      float xn = (vals[i]-mean)*rstd*lnw[col] + lnb[col];
      A[r][col] = f2bf(xn);
    }
  }
  __syncthreads();

  int lane = tid & 63, wave = tid >> 6;
  int row16 = lane & 15, kg = lane >> 4;
  int cb = wave * 32;

  auto gemm = [&](const short* __restrict__ B, const float* __restrict__ bias,
                  ushort* __restrict__ Ob){
    f32x4 acc[4][2] = {};
    #pragma unroll
    for (int kk = 0; kk < 128; kk += 32){
      int k0 = kk + kg*8;
      bf16x8 a0 = *(const bf16x8*)&A[ 0 + row16][k0];
      bf16x8 a1 = *(const bf16x8*)&A[16 + row16][k0];
      bf16x8 a2 = *(const bf16x8*)&A[32 + row16][k0];
      bf16x8 a3 = *(const bf16x8*)&A[48 + row16][k0];
      bf16x8 b0 = *(const bf16x8*)&B[(size_t)(cb +      row16)*128 + k0];
      bf16x8 b1 = *(const bf16x8*)&B[(size_t)(cb + 16 + row16)*128 + k0];
      acc[0][0] = __builtin_amdgcn_mfma_f32_16x16x32_bf16(a0, b0, acc[0][0], 0,0,0);
      acc[1][0] = __builtin_amdgcn_mfma_f32_16x16x32_bf16(a1, b0, acc[1][0], 0,0,0);
      acc[2][0] = __builtin_amdgcn_mfma_f32_16x16x32_bf16(a2, b0, acc[2][0], 0,0,0);
      acc[3][0] = __builtin_amdgcn_mfma_f32_16x16x32_bf16(a3, b0, acc[3][0], 0,0,0);
      acc[0][1] = __builtin_amdgcn_mfma_f32_16x16x32_bf16(a0, b1, acc[0][1], 0,0,0);
      acc[1][1] = __builtin_amdgcn_mfma_f32_16x16x32_bf16(a1, b1, acc[1][1], 0,0,0);
      acc[2][1] = __builtin_amdgcn_mfma_f32_16x16x32_bf16(a2, b1, acc[2][1], 0,0,0);
      acc[3][1] = __builtin_amdgcn_mfma_f32_16x16x32_bf16(a3, b1, acc[3][1], 0,0,0);
    }
    float bv0 = bias[cb + row16], bv1 = bias[cb + 16 + row16];
    #pragma unroll
    for (int rt = 0; rt < 4; ++rt){
      #pragma unroll
      for (int i = 0; i < 4; ++i){
        int row = rbase + rt*16 + kg*4 + i;
        if (row < N_NODES){
          Ob[(size_t)row*128 + cb      + row16] = (ushort)f2bf(acc[rt][0][i] + bv0);
          Ob[(size_t)row*128 + cb + 16 + row16] = (ushort)f2bf(acc[rt][1][i] + bv1);
        }
      }
    }
  };
  gemm(Wtq,  bq,  qb);
  gemm(Wtqm, bqm, qweb);
  gemm(Wtk,  bk,  kb);
  gemm(Wtv,  bv,  vb);
  gemm(Wts,  bs,  xrb);
}

// ---------------- edge attention aggregation: 2 nodes/wave, degree-sorted, pipelined ----------------
__global__ __launch_bounds__(256) void k_agg(
  const ushort* __restrict__ qb, const ushort* __restrict__ qweb,
  const ushort* __restrict__ kbf, const ushort* __restrict__ vbf,
  const ushort* __restrict__ eab, const float* __restrict__ We, const float* __restrict__ be,
  const int* __restrict__ esrc, const int* __restrict__ perm, const int2* __restrict__ rng,
  ushort* __restrict__ xrb)
{
  int tid = threadIdx.x;
  int gid = blockIdx.x*8 + (tid >> 5);
  int node = perm[gid];
  int2 r = rng[gid];
  int beg = r.x, end = r.y;
  int l = tid & 31;
  int d0 = l*4;
  int h  = l >> 2;
  int c0 = (l & 3)*4;

  uint2 qw = *(const uint2*)&qb[(size_t)node*128 + d0];
  float4 qv = make_float4(BF_LO(qw.x), BF_HI(qw.x), BF_LO(qw.y), BF_HI(qw.y));
  uint2 qew = *(const uint2*)&qweb[(size_t)node*128 + h*16 + c0];
  float4 qe = make_float4(BF_LO(qew.x), BF_HI(qew.x), BF_LO(qew.y), BF_HI(qew.y));
  float m = -INFINITY, den = 0.f;
  float4 va = make_float4(0,0,0,0);
  float4 S  = make_float4(0,0,0,0);

  int p = beg;

  // main loop: unroll 8 with next-batch index prefetch
  int s8[8];
  {
    bool have = (beg + 8 <= end);
    #pragma unroll
    for (int j = 0; j < 8; ++j) s8[j] = have ? esrc[beg + j] : 0;
  }
  for (; p + 8 <= end; p += 8){
    int n8[8];
    bool more = (p + 16 <= end);
    #pragma unroll
    for (int j = 0; j < 8; ++j) n8[j] = more ? esrc[p + 8 + j] : 0;
    uint2 kw[8], vw[8], ew[8];
    #pragma unroll
    for (int j = 0; j < 8; ++j){
      kw[j] = *(const uint2*)&kbf[(size_t)s8[j]*128 + d0];
      vw[j] = *(const uint2*)&vbf[(size_t)s8[j]*128 + d0];
      ew[j] = *(const uint2*)&eab[(size_t)(p+j)*16 + c0];
    }
    float sc[8];
    #pragma unroll
    for (int j = 0; j < 8; ++j){
      float pp = qv.x*BF_LO(kw[j].x) + qv.y*BF_HI(kw[j].x)
               + qv.z*BF_LO(kw[j].y) + qv.w*BF_HI(kw[j].y)
               + qe.x*BF_LO(ew[j].x) + qe.y*BF_HI(ew[j].x)
               + qe.z*BF_LO(ew[j].y) + qe.w*BF_HI(ew[j].y);
      pp += __shfl_xor(pp,1,64); pp += __shfl_xor(pp,2,64);
      sc[j] = pp*0.25f;
    }
    float mn = m;
    #pragma unroll
    for (int j = 0; j < 8; ++j) mn = fmaxf(mn, sc[j]);
    float corr = __expf(m - mn);
    float w[8]; float ds = 0.f;
    #pragma unroll
    for (int j = 0; j < 8; ++j){ w[j] = __expf(sc[j]-mn); ds += w[j]; }
    den = den*corr + ds;
    float ax=0.f, ay=0.f, az=0.f, aw2=0.f, sx=0.f, sy=0.f, sz=0.f, sw=0.f;
    #pragma unroll
    for (int j = 0; j < 8; ++j){
      ax += w[j]*BF_LO(vw[j].x); ay += w[j]*BF_HI(vw[j].x);
      az += w[j]*BF_LO(vw[j].y); aw2+= w[j]*BF_HI(vw[j].y);
      sx += w[j]*BF_LO(ew[j].x); sy += w[j]*BF_HI(ew[j].x);
      sz += w[j]*BF_LO(ew[j].y); sw += w[j]*BF_HI(ew[j].y);
    }
    va.x = va.x*corr + ax; va.y = va.y*corr + ay;
    va.z = va.z*corr + az; va.w = va.w*corr + aw2;
    S.x  = S.x *corr + sx; S.y  = S.y *corr + sy;
    S.z  = S.z *corr + sz; S.w  = S.w *corr + sw;
    m = mn;
    #pragma unroll
    for (int j = 0; j < 8; ++j) s8[j] = n8[j];
  }

#define AGG_STEP(J)                                                            \
  {                                                                            \
    int sidx[J];                                                               \
    _Pragma("unroll")                                                          \
    for (int j = 0; j < J; ++j) sidx[j] = esrc[p+j];                           \
    uint2 kw[J], vw[J], ew[J];                                                 \
    _Pragma("unroll")                                                          \
    for (int j = 0; j < J; ++j){                                               \
      kw[j] = *(const uint2*)&kbf[(size_t)sidx[j]*128 + d0];                   \
      vw[j] = *(const uint2*)&vbf[(size_t)sidx[j]*128 + d0];                   \
      ew[j] = *(const uint2*)&eab[(size_t)(p+j)*16 + c0];                      \
    }                                                                          \
    float sc[J];                                                               \
    _Pragma("unroll")                                                          \
    for (int j = 0; j < J; ++j){                                               \
      float pp = qv.x*BF_LO(kw[j].x) + qv.y*BF_HI(kw[j].x)                     \
               + qv.z*BF_LO(kw[j].y) + qv.w*BF_HI(kw[j].y)                     \
               + qe.x*BF_LO(ew[j].x) + qe.y*BF_HI(ew[j].x)                     \
               + qe.z*BF_LO(ew[j].y) + qe.w*BF_HI(ew[j].y);                    \
      pp += __shfl_xor(pp,1,64); pp += __shfl_xor(pp,2,64);                    \
      sc[j] = pp*0.25f;                                                        \
    }                                                                          \
    float mn = m;                                                              \
    _Pragma("unroll")                                                          \
    for (int j = 0; j < J; ++j) mn = fmaxf(mn, sc[j]);                         \
    float corr = __expf(m - mn);                                               \
    float w[J]; float ds = 0.f;                                                \
    _Pragma("unroll")                                                          \
    for (int j = 0; j < J; ++j){ w[j] = __expf(sc[j]-mn); ds += w[j]; }        \
    den = den*corr + ds;                                                       \
    float ax=0.f, ay=0.f, az=0.f, aw2=0.f, sx=0.f, sy=0.f, sz=0.f, sw=0.f;     \
    _Pragma("unroll")                                                          \
    for (int j = 0; j < J; ++j){                                               \
      ax += w[j]*BF_LO(vw[j].x); ay += w[j]*BF_HI(vw[j].x);                    \
      az += w[j]*BF_LO(vw[j].y); aw2+= w[j]*BF_HI(vw[j].y);                    \
      sx += w[j]*BF_LO(ew[j].x); sy += w[j]*BF_HI(ew[j].x);                    \
      sz += w[j]*BF_LO(ew[j].y); sw += w[j]*BF_HI(ew[j].y);                    \
    }                                                                          \
    va.x = va.x*corr + ax; va.y = va.y*corr + ay;                              \
    va.z = va.z*corr + az; va.w = va.w*corr + aw2;                             \
    S.x  = S.x *corr + sx; S.y  = S.y *corr + sy;                              \
    S.z  = S.z *corr + sz; S.w  = S.w *corr + sw;                              \
    m = mn;                                                                    \
  }

  for (; p + 4 <= end; p += 4) AGG_STEP(4)
  for (; p < end; ++p){
    int s = esrc[p];
    uint2 kw = *(const uint2*)&kbf[(size_t)s*128 + d0];
    uint2 vw = *(const uint2*)&vbf[(size_t)s*128 + d0];
    uint2 ew = *(const uint2*)&eab[(size_t)p*16 + c0];
    float pp = qv.x*BF_LO(kw.x) + qv.y*BF_HI(kw.x)
             + qv.z*BF_LO(kw.y) + qv.w*BF_HI(kw.y)
             + qe.x*BF_LO(ew.x) + qe.y*BF_HI(ew.x)
             + qe.z*BF_LO(ew.y) + qe.w*BF_HI(ew.y);
    pp += __shfl_xor(pp,1,64); pp += __shfl_xor(pp,2,64);
    float sc = pp*0.25f;
    float mn = fmaxf(m, sc);
    float corr = __expf(m - mn);
    float pe = __expf(sc - mn);
    den = den*corr + pe;
    va.x = va.x*corr + pe*BF_LO(vw.x);
    va.y = va.y*corr + pe*BF_HI(vw.x);
    va.z = va.z*corr + pe*BF_LO(vw.y);
    va.w = va.w*corr + pe*BF_HI(vw.y);
    S.x = S.x*corr + pe*BF_LO(ew.x);
    S.y = S.y*corr + pe*BF_HI(ew.x);
    S.z = S.z*corr + pe*BF_LO(ew.y);
    S.w = S.w*corr + pe*BF_HI(ew.y);
    m = mn;
  }

  if (end > beg){
    float inv = 1.0f/den;
    float4 acc = va;
    int gb = (tid & 63) & 60;
    #pragma unroll
    for (int g = 0; g < 4; ++g){
      float s0 = __shfl(S.x, gb+g, 64);
      float s1 = __shfl(S.y, gb+g, 64);
      float s2 = __shfl(S.z, gb+g, 64);
      float s3 = __shfl(S.w, gb+g, 64);
      float4 w0 = *(const float4*)&We[(g*4+0)*128 + d0];
      float4 w1 = *(const float4*)&We[(g*4+1)*128 + d0];
      float4 w2 = *(const float4*)&We[(g*4+2)*128 + d0];
      float4 w3 = *(const float4*)&We[(g*4+3)*128 + d0];
      acc.x += s0*w0.x + s1*w1.x + s2*w2.x + s3*w3.x;
      acc.y += s0*w0.y + s1*w1.y + s2*w2.y + s3*w3.y;
      acc.z += s0*w0.z + s1*w1.z + s2*w2.z + s3*w3.z;
      acc.w += s0*w0.w + s1*w1.w + s2*w2.w + s3*w3.w;
    }
    float4 bev = *(const float4*)&be[d0];
    uint2 xw = *(const uint2*)&xrb[(size_t)node*128 + d0];
    float4 xv = make_float4(BF_LO(xw.x), BF_HI(xw.x), BF_LO(xw.y), BF_HI(xw.y));
    xv.x += acc.x*inv + bev.x;
    xv.y += acc.y*inv + bev.y;
    xv.z += acc.z*inv + bev.z;
    xv.w += acc.w*inv + bev.w;
    uint2 ow;
    ow.x = pkbf(xv.x, xv.y);
    ow.y = pkbf(xv.z, xv.w);
    *(uint2*)&xrb[(size_t)node*128 + d0] = ow;
  }
}

// ---------------- fused post+MLP: res in LDS; hidden in 4x128 quarter passes ----------------
__global__ __launch_bounds__(256) void k_postmlp(
  const ushort* __restrict__ aggout, const float* __restrict__ x,
  const short* __restrict__ Wtp, const float* __restrict__ bp,
  const float* __restrict__ lnw, const float* __restrict__ lnb,
  const short* __restrict__ W1t, const float* __restrict__ b1,
  const short* __restrict__ W2t, const float* __restrict__ b2,
  float* __restrict__ out)
{
  __shared__ short A[32][136];
  __shared__ float rf[32][132];
  __shared__ short Hd[32][136];
  int tid = threadIdx.x;
  int rbase = blockIdx.x * 32;
  int lane = tid & 63, wave = tid >> 6;
  int row16 = lane & 15, kg = lane >> 4;

  // phase 0: load bf16 aggout tile
  for (int idx = tid; idx < 512; idx += 256){
    int r = idx >> 4, g = idx & 15;
    *(uint4*)&A[r][g*8] = *(const uint4*)&aggout[((size_t)(rbase + r))*128 + g*8];
  }
  __syncthreads();

  // phase 1: rf = A@Wtp + bp + x
  {
    int cb = wave * 32;
    f32x4 acc[2][2] = {};
    #pragma unroll
    for (int kk = 0; kk < 128; kk += 32){
      int k0 = kk + kg*8;
      bf16x8 a0 = *(const bf16x8*)&A[     row16][k0];
      bf16x8 a1 = *(const bf16x8*)&A[16 + row16][k0];
      bf16x8 b0 = *(const bf16x8*)&Wtp[(size_t)(cb +      row16)*128 + k0];
      bf16x8 b1 = *(const bf16x8*)&Wtp[(size_t)(cb + 16 + row16)*128 + k0];
      acc[0][0] = __builtin_amdgcn_mfma_f32_16x16x32_bf16(a0, b0, acc[0][0], 0,0,0);
      acc[1][0] = __builtin_amdgcn_mfma_f32_16x16x32_bf16(a1, b0, acc[1][0], 0,0,0);
      acc[0][1] = __builtin_amdgcn_mfma_f32_16x16x32_bf16(a0, b1, acc[0][1], 0,0,0);
      acc[1][1] = __builtin_amdgcn_mfma_f32_16x16x32_bf16(a1, b1, acc[1][1], 0,0,0);
    }
    float bv0 = bp[cb + row16], bv1 = bp[cb + 16 + row16];
    #pragma unroll
    for (int rt = 0; rt < 2; ++rt){
      #pragma unroll
      for (int i = 0; i < 4; ++i){
        int rl = rt*16 + kg*4 + i;
        int row = rbase + rl;
        float v0 = acc[rt][0][i] + bv0;
        float v1 = acc[rt][1][i] + bv1;
        if (row < N_NODES){
          v0 += x[(size_t)row*128 + cb      + row16];
          v1 += x[(size_t)row*128 + cb + 16 + row16];
        }
        rf[rl][cb      + row16] = v0;
        rf[rl][cb + 16 + row16] = v1;
      }
    }
  }
  __syncthreads();

  // phase 2: LN(rf) -> A (bf16); 8 threads/row, 16 cols each
  {
    int r = tid >> 3, j = tid & 7;
    float vals[16];
    #pragma unroll
    for (int i = 0; i < 4; ++i){
      float4 t = *(const float4*)&rf[r][j*16 + i*4];
      vals[i*4+0]=t.x; vals[i*4+1]=t.y; vals[i*4+2]=t.z; vals[i*4+3]=t.w;
    }
    float s = 0.f, s2 = 0.f;
    #pragma unroll
    for (int i = 0; i < 16; ++i){ s += vals[i]; s2 += vals[i]*vals[i]; }
    s  += __shfl_xor(s, 1, 64);  s  += __shfl_xor(s, 2, 64);  s  += __shfl_xor(s, 4, 64);
    s2 += __shfl_xor(s2, 1, 64); s2 += __shfl_xor(s2, 2, 64); s2 += __shfl_xor(s2, 4, 64);
    float mean = s * 0.0078125f;
    float var  = s2 * 0.0078125f - mean*mean;
    float rstd = rsqrtf(var + 1e-5f);
    #pragma unroll
    for (int i = 0; i < 16; ++i){
      int col = j*16 + i;
      A[r][col] = f2bf((vals[i]-mean)*rstd*lnw[col] + lnb[col]);
    }
  }

  // phases 3/4: hidden in FOUR 128-col quarter passes; acc2 persists
  f32x4 acc2[2][2] = {};
  #pragma unroll
  for (int qt = 0; qt < 4; ++qt){
    __syncthreads();   // qt 0: A ready; later: protect Hd from previous phase-4 readers
    // phase 3: Hd = bf16(gelu(A@W1qt + b1qt)); each wave 32 cols
    {
      f32x4 acc[2][2] = {};
      #pragma unroll
      for (int kk = 0; kk < 128; kk += 32){
        int k0 = kk + kg*8;
        bf16x8 a0 = *(const bf16x8*)&A[     row16][k0];
        bf16x8 a1 = *(const bf16x8*)&A[16 + row16][k0];
        #pragma unroll
        for (int ct = 0; ct < 2; ++ct){
          bf16x8 b = *(const bf16x8*)&W1t[(size_t)(qt*128 + wave*32 + ct*16 + row16)*128 + k0];
          acc[0][ct] = __builtin_amdgcn_mfma_f32_16x16x32_bf16(a0, b, acc[0][ct], 0,0,0);
          acc[1][ct] = __builtin_amdgcn_mfma_f32_16x16x32_bf16(a1, b, acc[1][ct], 0,0,0);
        }
      }
      #pragma unroll
      for (int ct = 0; ct < 2; ++ct){
        int col = wave*32 + ct*16 + row16;       // local 0..127
        float bb = b1[qt*128 + col];
        #pragma unroll
        for (int rt = 0; rt < 2; ++rt)
          #pragma unroll
          for (int i = 0; i < 4; ++i)
            Hd[rt*16 + kg*4 + i][col] = f2bf(gelu_f(acc[rt][ct][i] + bb));
      }
    }
    __syncthreads();
    // phase 4 partial: acc2 += Hd @ W2qt slice; each wave 32 out cols, K=128
    {
      int cb = wave * 32;
      #pragma unroll
      for (int kc = 0; kc < 4; ++kc){
        int k0 = kc*32 + kg*8;                   // local 0..127
        bf16x8 a0 = *(const bf16x8*)&Hd[     row16][k0];
        bf16x8 a1 = *(const bf16x8*)&Hd[16 + row16][k0];
        bf16x8 b0 = *(const bf16x8*)&W2t[(size_t)(cb +      row16)*512 + qt*128 + k0];
        bf16x8 b1 = *(const bf16x8*)&W2t[(size_t)(cb + 16 + row16)*512 + qt*128 + k0];
        acc2[0][0] = __builtin_amdgcn_mfma_f32_16x16x32_bf16(a0, b0, acc2[0][0], 0,0,0);
        acc2[1][0] = __builtin_amdgcn_mfma_f32_16x16x32_bf16(a1, b0, acc2[1][0], 0,0,0);
        acc2[0][1] = __builtin_amdgcn_mfma_f32_16x16x32_bf16(a0, b1, acc2[0][1], 0,0,0);
        acc2[1][1] = __builtin_amdgcn_mfma_f32_16x16x32_bf16(a1, b1, acc2[1][1], 0,0,0);
      }
    }
  }

  // epilogue: out = acc2 + b2 + rf
  {
    int cb = wave * 32;
    float bv0 = b2[cb + row16], bv1 = b2[cb + 16 + row16];
    #pragma unroll
    for (int rt = 0; rt < 2; ++rt){
      #pragma unroll
      for (int i = 0; i < 4; ++i){
        int rl = rt*16 + kg*4 + i;
        int row = rbase + rl;
        if (row < N_NODES){
          out[(size_t)row*128 + cb      + row16] = acc2[rt][0][i] + bv0 + rf[rl][cb      + row16];
          out[(size_t)row*128 + cb + 16 + row16] = acc2[rt][1][i] + bv1 + rf[rl][cb + 16 + row16];
        }
      }
    }
  }
}

extern "C" void kernel_launch(void* const* d_in, const int* in_sizes, int n_in,
                              void* d_out, int out_size, void* d_ws, size_t ws_size,
                              hipStream_t stream)
{
  const float* x        = (const float*)d_in[0];
  const float* edge_attr= (const float*)d_in[1];
  const int*   edge_index=(const int*)d_in[2];
  const float* Wq = (const float*)d_in[3];  const float* bq = (const float*)d_in[4];
  const float* Wk = (const float*)d_in[5];  const float* bk = (const float*)d_in[6];
  const float* Wv = (const float*)d_in[7];  const float* bv = (const float*)d_in[8];
  const float* Wss= (const float*)d_in[9];  const float* bss= (const float*)d_in[10];
  const float* We = (const float*)d_in[11]; const float* be = (const float*)d_in[12];
  const float* Wp = (const float*)d_in[13]; const float* bp = (const float*)d_in[14];
  const float* lnaw=(const float*)d_in[15]; const float* lnab=(const float*)d_in[16];
  const float* lnmw=(const float*)d_in[17]; const float* lnmb=(const float*)d_in[18];
  const float* W1 = (const float*)d_in[19]; const float* b1 = (const float*)d_in[20];
  const float* W2 = (const float*)d_in[21]; const float* b2 = (const float*)d_in[22];

  float* ws = (float*)d_ws;
  // N_PAD = 50048 rows; bf16 [NP][128] = NPH float units
  const size_t NPH = 3203072;
  ushort* qb   = (ushort*)ws;
  ushort* qweb = (ushort*)(ws + NPH);
  ushort* kbf  = (ushort*)(ws + 2*NPH);
  ushort* vbf  = (ushort*)(ws + 3*NPH);
  ushort* xrb  = (ushort*)(ws + 4*NPH);
  ushort* eab  = (ushort*)(ws + 5*NPH);        // bf16 [E][16]
  short* wts   = (short*)(ws + 25624576);
  short* Wtq   = wts;
  short* Wtk   = wts + 16384;
  short* Wtv   = wts + 32768;
  short* Wts_  = wts + 49152;
  short* Wtp   = wts + 65536;
  short* Wtqm  = wts + 81920;
  short* W1t   = wts + 98304;                  // [512][128]
  short* W2t   = wts + 163840;                 // [128][512]
  float* bqm   = ws + 25624576 + 114688 + 16384;
  int*   iw    = (int*)(bqm + 128);
  int* deg     = iw;                           // 50000
  int* hist    = iw + 50000;                   // 64
  int* histcur = iw + 50064;                   // 64
  int* bsum    = iw + 50128;                   // 196
  int* bbase   = iw + 50324;                   // 196
  int* cursor  = iw + 50520;                   // 50000
  int* perm    = iw + 100520;                  // 50000
  int2* rng    = (int2*)(iw + 150520);         // 50000 pairs (even offset)
  int* esrc    = iw + 250520;                  // 800000

  const int* srcIdx = edge_index;
  const int* dstIdx = edge_index + N_EDGES;

  // unified weight prep (single launch)
  Prep pa;
  pa.src[0]=Wq; pa.src[1]=Wk; pa.src[2]=Wv; pa.src[3]=Wss; pa.src[4]=Wp;
  pa.dst[0]=Wtq; pa.dst[1]=Wtk; pa.dst[2]=Wtv; pa.dst[3]=Wts_; pa.dst[4]=Wtp;
  pa.Wq=Wq; pa.We=We; pa.bq=bq; pa.Wtqm=Wtqm; pa.bqm=bqm;
  pa.W1=W1; pa.W1t=W1t; pa.W2=W2; pa.W2t=W2t;
  k_prep<<<896, 256, 0, stream>>>(pa);

  // CSR + degree-sort
  hipMemsetAsync(deg, 0, 50064*sizeof(int), stream);   // deg + hist
  k_deg<<<(N_EDGES+255)/256, 256, 0, stream>>>(dstIdx, deg);
  k_bsum<<<196, 256, 0, stream>>>(deg, bsum, hist);
  k_bscan<<<1, 256, 0, stream>>>(bsum, bbase, hist, histcur);
  k_applyperm<<<196, 256, 0, stream>>>(deg, bbase, histcur, cursor, perm, rng);
  k_scatter<<<(N_EDGES+255)/256, 256, 0, stream>>>(dstIdx, srcIdx, edge_attr, cursor, esrc, eab,
                                                   (float*)d_out + (size_t)N_NODES*128);

  // main pipeline
  k_nodeproj<<<782, 256, 0, stream>>>(x, lnaw, lnab, Wtq, Wtqm, Wtk, Wtv, Wts_,
                                      bq, bqm, bk, bv, bss, qb, qweb, kbf, vbf, xrb);
  k_agg<<<N_NODES/8, 256, 0, stream>>>(qb, qweb, kbf, vbf, eab, We, be,
                                       esrc, perm, rng, xrb);
  k_postmlp<<<1564, 256, 0, stream>>>(xrb, x, Wtp, bp, lnmw, lnmb,
                                      W1t, b1, W2t, b2, (float*)d_out);
}